// Round 5
// baseline (151.505 us; speedup 1.0000x reference)
//
#include <hip/hip_runtime.h>
#include <math.h>

#define NCH   64
#define IMW   512
#define NPTS  150000
#define TOTAL (2 * NPTS)
#define IMHW  (512 * 512)
#define HID   32
#define NBINS 32768   // 2 batches x 512 y x 32 x-cells (16 px = one 64B line)
#define CPB   16      // cells per block (256 threads = 16 cells x 16 pixels)

// ---------- sort pass ----------

__global__ __launch_bounds__(256) void hist_kernel(const int* __restrict__ coords,
                                                   int* __restrict__ hist) {
    int gid = blockIdx.x * blockDim.x + threadIdx.x;
    if (gid >= TOTAL) return;
    const int y = coords[gid * 3 + 1];
    const int x = coords[gid * 3 + 2];
    const int b = (gid >= NPTS) ? 1 : 0;
    const int key = (b << 14) | (y << 5) | (x >> 4);
    atomicAdd(&hist[key], 1);
}

// single-block exclusive scan of 32768 ints (1024 thr x 32 each)
// writes binStart (preserved) and binPos (mutated by scatter)
__global__ __launch_bounds__(1024) void scan_kernel(const int* __restrict__ hist,
                                                    int* __restrict__ binStart,
                                                    int* __restrict__ binPos) {
    __shared__ int lds[1024];
    const int t = threadIdx.x;
    const int base = t * 32;
    int loc[32];
    int s = 0;
    #pragma unroll
    for (int i = 0; i < 32; ++i) { loc[i] = s; s += hist[base + i]; }
    lds[t] = s;
    __syncthreads();
    for (int d = 1; d < 1024; d <<= 1) {
        int v = lds[t];
        int add = (t >= d) ? lds[t - d] : 0;
        __syncthreads();
        lds[t] = v + add;
        __syncthreads();
    }
    const int excl = lds[t] - s;
    #pragma unroll
    for (int i = 0; i < 32; ++i) {
        const int v = excl + loc[i];
        binStart[base + i] = v;
        binPos[base + i]   = v;
    }
}

__global__ __launch_bounds__(256) void scatter_kernel(const int* __restrict__ coords,
                                                      int* __restrict__ binPos,
                                                      int* __restrict__ perm) {
    int gid = blockIdx.x * blockDim.x + threadIdx.x;
    if (gid >= TOTAL) return;
    const int y = coords[gid * 3 + 1];
    const int x = coords[gid * 3 + 2];
    const int b = (gid >= NPTS) ? 1 : 0;
    const int key = (b << 14) | (y << 5) | (x >> 4);
    const int pos = atomicAdd(&binPos[key], 1);
    perm[pos] = gid;
}

// ---------- cell-major fused kernel ----------
// Phase 1: each thread owns one pixel of one cell; reads all 128 channels
//          coalesced (16 lanes = one 64B line) and accumulates
//          h_img[32] = sum_c img[c]*W1[c]; parks in LDS.
// Phase 2: block's points (via sort) finish: +offsets rows, bias, GELU, W2.

__global__ __launch_bounds__(256) void ffd_cell_kernel(
    const float* __restrict__ before,
    const float* __restrict__ after,
    const float* __restrict__ offsets,
    const int*   __restrict__ coords,
    const float* __restrict__ W1,   // [131, 32]
    const float* __restrict__ b1,   // [32]
    const float* __restrict__ W2,   // [32, 3]
    const float* __restrict__ b2,   // [3]
    const int*   __restrict__ perm,
    const int*   __restrict__ binStart,
    float*       __restrict__ out)  // [2, 150000, 3]
{
    __shared__ float himg[CPB * 16 * 33];   // [cell][x][32+pad]

    const int tid  = threadIdx.x;
    const int cl   = tid >> 4;     // 0..15  local cell
    const int xo   = tid & 15;     // 0..15  pixel within line
    const int cell = blockIdx.x * CPB + cl;
    const int b    = cell >> 14;
    const int y    = (cell >> 5) & 511;
    const int x    = (cell & 31) * 16 + xo;

    const long pix = (long)b * (64L * IMHW) + (long)y * IMW + x;
    const float* p0 = before + pix;
    const float* p1 = after  + pix;

    float acc[HID];
    #pragma unroll
    for (int h = 0; h < HID; ++h) acc[h] = 0.f;

    float g[16];
    // before: W1 rows 0..63
    #pragma unroll
    for (int ck = 0; ck < 4; ++ck) {
        #pragma unroll
        for (int j = 0; j < 16; ++j) g[j] = p0[(long)(ck * 16 + j) * IMHW];
        #pragma unroll
        for (int j = 0; j < 16; ++j) {
            const float* wr = W1 + (ck * 16 + j) * HID;
            #pragma unroll
            for (int h = 0; h < HID; ++h) acc[h] = fmaf(g[j], wr[h], acc[h]);
        }
    }
    // after: W1 rows 64..127
    #pragma unroll
    for (int ck = 0; ck < 4; ++ck) {
        #pragma unroll
        for (int j = 0; j < 16; ++j) g[j] = p1[(long)(ck * 16 + j) * IMHW];
        #pragma unroll
        for (int j = 0; j < 16; ++j) {
            const float* wr = W1 + (64 + ck * 16 + j) * HID;
            #pragma unroll
            for (int h = 0; h < HID; ++h) acc[h] = fmaf(g[j], wr[h], acc[h]);
        }
    }

    {
        float* hp = &himg[(cl * 16 + xo) * 33];
        #pragma unroll
        for (int h = 0; h < HID; ++h) hp[h] = acc[h];
    }
    __syncthreads();

    // ---- phase 2: finish this block's points ----
    const int bfc   = blockIdx.x * CPB;
    const int start = binStart[bfc];
    const int end   = (bfc + CPB < NBINS) ? binStart[bfc + CPB] : TOTAL;

    const float* r0 = W1 + 128 * HID;
    const float* r1 = W1 + 129 * HID;
    const float* r2 = W1 + 130 * HID;

    for (int i = start + tid; i < end; i += 256) {
        const int pid = perm[i];
        const long pbase = (long)pid * 3;
        const int py = coords[pbase + 1];
        const int px = coords[pbase + 2];
        const int pb = (pid >= NPTS) ? 1 : 0;
        const int pcl = ((pb << 14) | (py << 5) | (px >> 4)) - bfc;
        const float* hsrc = &himg[(pcl * 16 + (px & 15)) * 33];

        const float o0 = offsets[pbase + 0];
        const float o1 = offsets[pbase + 1];
        const float o2 = offsets[pbase + 2];

        float q0 = b2[0], q1 = b2[1], q2 = b2[2];
        #pragma unroll
        for (int h = 0; h < HID; ++h) {
            float v = hsrc[h] + b1[h];
            v = fmaf(o2, r2[h], fmaf(o1, r1[h], fmaf(o0, r0[h], v)));
            v = 0.5f * v * (1.0f + erff(v * 0.70710678118654752f));
            q0 = fmaf(v, W2[h * 3 + 0], q0);
            q1 = fmaf(v, W2[h * 3 + 1], q1);
            q2 = fmaf(v, W2[h * 3 + 2], q2);
        }
        out[pbase + 0] = q0;
        out[pbase + 1] = q1;
        out[pbase + 2] = q2;
    }
}

// ---------- fallback (no workspace): one thread per point ----------

__global__ __launch_bounds__(256) void ffd_naive_kernel(
    const float* __restrict__ before,
    const float* __restrict__ after,
    const float* __restrict__ offsets,
    const int*   __restrict__ coords,
    const float* __restrict__ W1,
    const float* __restrict__ b1,
    const float* __restrict__ W2,
    const float* __restrict__ b2,
    float*       __restrict__ out)
{
    int gid = blockIdx.x * blockDim.x + threadIdx.x;
    if (gid >= TOTAL) return;
    const int b = (gid >= NPTS) ? 1 : 0;
    const long pbase = (long)gid * 3;
    const int y = coords[pbase + 1];
    const int x = coords[pbase + 2];

    float acc[HID];
    #pragma unroll
    for (int h = 0; h < HID; ++h) acc[h] = b1[h];

    const long img_off = (long)b * (64L * IMHW) + (long)y * IMW + x;
    const float* bp = before + img_off;
    const float* ap = after  + img_off;

    for (int c = 0; c < NCH; ++c) {
        const float v = bp[(long)c * IMHW];
        const float* wr = W1 + c * HID;
        #pragma unroll
        for (int h = 0; h < HID; ++h) acc[h] = fmaf(v, wr[h], acc[h]);
    }
    for (int c = 0; c < NCH; ++c) {
        const float v = ap[(long)c * IMHW];
        const float* wr = W1 + (64 + c) * HID;
        #pragma unroll
        for (int h = 0; h < HID; ++h) acc[h] = fmaf(v, wr[h], acc[h]);
    }
    #pragma unroll
    for (int k = 0; k < 3; ++k) {
        const float v = offsets[pbase + k];
        const float* wr = W1 + (128 + k) * HID;
        #pragma unroll
        for (int h = 0; h < HID; ++h) acc[h] = fmaf(v, wr[h], acc[h]);
    }
    float q0 = b2[0], q1 = b2[1], q2 = b2[2];
    #pragma unroll
    for (int h = 0; h < HID; ++h) {
        const float xh = acc[h];
        const float v = 0.5f * xh * (1.0f + erff(xh * 0.70710678118654752f));
        q0 = fmaf(v, W2[h * 3 + 0], q0);
        q1 = fmaf(v, W2[h * 3 + 1], q1);
        q2 = fmaf(v, W2[h * 3 + 2], q2);
    }
    out[pbase + 0] = q0;
    out[pbase + 1] = q1;
    out[pbase + 2] = q2;
}

extern "C" void kernel_launch(void* const* d_in, const int* in_sizes, int n_in,
                              void* d_out, int out_size, void* d_ws, size_t ws_size,
                              hipStream_t stream) {
    const float* before  = (const float*)d_in[0];
    const float* after   = (const float*)d_in[1];
    const float* offsets = (const float*)d_in[2];
    const int*   coords  = (const int*)  d_in[3];
    const float* W1      = (const float*)d_in[4];
    const float* b1      = (const float*)d_in[5];
    const float* W2      = (const float*)d_in[6];
    const float* b2      = (const float*)d_in[7];
    float* out = (float*)d_out;

    const int block = 256;
    const int sgrid = (TOTAL + block - 1) / block;

    // ws layout: hist[NBINS] | binStart[NBINS] | binPos[NBINS] | perm[TOTAL]
    const size_t need = (size_t)(3 * NBINS + TOTAL) * sizeof(int);

    if (ws_size >= need) {
        int* hist     = (int*)d_ws;
        int* binStart = hist + NBINS;
        int* binPos   = binStart + NBINS;
        int* perm     = binPos + NBINS;

        hipMemsetAsync(hist, 0, NBINS * sizeof(int), stream);
        hist_kernel<<<sgrid, block, 0, stream>>>(coords, hist);
        scan_kernel<<<1, 1024, 0, stream>>>(hist, binStart, binPos);
        scatter_kernel<<<sgrid, block, 0, stream>>>(coords, binPos, perm);
        ffd_cell_kernel<<<NBINS / CPB, block, 0, stream>>>(
            before, after, offsets, coords, W1, b1, W2, b2, perm, binStart, out);
    } else {
        ffd_naive_kernel<<<sgrid, block, 0, stream>>>(before, after, offsets, coords,
                                                      W1, b1, W2, b2, out);
    }
}